// Round 1
// baseline (87.398 us; speedup 1.0000x reference)
//
#include <hip/hip_runtime.h>
#include <hip/hip_bf16.h>

#define BATCH 4096
#define NROWS 8192
#define DIM   128

typedef __bf16 bf16x8 __attribute__((ext_vector_type(8)));
typedef __bf16 bf16x2 __attribute__((ext_vector_type(2)));
typedef float  f32x4  __attribute__((ext_vector_type(4)));

typedef const __attribute__((address_space(1))) unsigned int* gptr_t;
typedef __attribute__((address_space(3))) unsigned int* lptr_t;

// ---------------------------------------------------------------------------
// Kernel 1: row-normalize z = concat(zx, zy), write bf16 zn [8192 x 128]
// One wave per row; lane holds 2 floats.
// ---------------------------------------------------------------------------
__global__ __launch_bounds__(256) void normalize_kernel(
    const float* __restrict__ zx, const float* __restrict__ zy,
    ushort* __restrict__ zn)
{
  const int tid  = threadIdx.x;
  const int lane = tid & 63;
  const int w    = tid >> 6;
  const int row  = blockIdx.x * 4 + w;
  const float* src = (row < BATCH) ? (zx + (size_t)row * DIM)
                                   : (zy + (size_t)(row - BATCH) * DIM);
  float2 v = ((const float2*)src)[lane];
  float ss = v.x * v.x + v.y * v.y;
#pragma unroll
  for (int off = 1; off < 64; off <<= 1)
    ss += __shfl_xor(ss, off, 64);
  float inv = 1.0f / fmaxf(sqrtf(ss), 1e-8f);
  bf16x2 st;
  st.x = (__bf16)(v.x * inv);
  st.y = (__bf16)(v.y * inv);
  reinterpret_cast<bf16x2*>(zn + (size_t)row * DIM)[lane] = st;
}

// ---------------------------------------------------------------------------
// Kernel 2: fused sim = (zn zn^T)/TEMP with exp-sum epilogue.
// Grid (64 row-blocks, 8 col-strips); block = 256 threads = 4 waves (2x2).
// Each block: rows rb*128..+128, cols strip*1024..+1024 in 8 col-tiles of 128.
// S[i] += sum_{j in strip, j != i} exp(sim[i,j] - 2);  P[i] = sim[i, i^4096].
// A-fragments (K=128) live in registers; B-tile staged to LDS via
// global_load_lds(16B) with XOR chunk swizzle (kills 16-way bank conflicts).
// ---------------------------------------------------------------------------
__global__ __launch_bounds__(256, 2) void simloss_kernel(
    const ushort* __restrict__ zn, float* __restrict__ S, float* __restrict__ P)
{
  __shared__ ushort Bs[128 * 128];   // 32 KiB, swizzled 16B-chunk layout
  const int tid  = threadIdx.x;
  const int lane = tid & 63;
  const int w    = tid >> 6;
  const int wr   = w >> 1, wc = w & 1;
  const int rb    = blockIdx.x;   // 0..63
  const int strip = blockIdx.y;   // 0..7
  const int q    = lane >> 4;     // quad 0..3
  const int l15  = lane & 15;

  // A fragments: A[m = l15][k = q*8 + j], rows rb*128 + wr*64 + mi*16 + l15
  bf16x8 af[4][4];
  {
    const int arow = rb * 128 + wr * 64 + l15;
#pragma unroll
    for (int mi = 0; mi < 4; ++mi)
#pragma unroll
      for (int ks = 0; ks < 4; ++ks) {
        const ushort* ap = zn + (size_t)(arow + mi * 16) * DIM + ks * 32 + q * 8;
        af[mi][ks] = *reinterpret_cast<const bf16x8*>(ap);
      }
  }

  float Srow[4][4];
#pragma unroll
  for (int mi = 0; mi < 4; ++mi)
#pragma unroll
    for (int r = 0; r < 4; ++r) Srow[mi][r] = 0.f;

  const float K1 = 2.8853900817779268f;  // (1/TEMP) * log2(e); sim shift folded: -K1

  for (int it = 0; it < 8; ++it) {
    const int ct = strip * 8 + it;       // col-tile index 0..63
    const int C0 = ct * 128;

    __syncthreads();  // WAR: previous iter's ds_reads done before restage
    // Stage B tile: 128 rows x 16 chunks (16B each). Chunk (row, c) stored at
    // LDS chunk row*16 + (c ^ (row&15)). global_load_lds dest = base + lane*16.
#pragma unroll
    for (int j = 0; j < 8; ++j) {
      const int Lbase = w * 512 + j * 64;          // uniform per wave
      const int row   = w * 32 + j * 4 + q;        // (Lbase+lane)>>4
      const int c     = l15 ^ (row & 15);
      const ushort* g = zn + (size_t)(C0 + row) * DIM + c * 8;
      __builtin_amdgcn_global_load_lds((gptr_t)g, (lptr_t)(Bs + Lbase * 8), 16, 0, 0);
    }
    __syncthreads();  // compiler drains vmcnt(0) before s_barrier

    f32x4 acc[4][4];
#pragma unroll
    for (int mi = 0; mi < 4; ++mi)
#pragma unroll
      for (int ni = 0; ni < 4; ++ni)
        acc[mi][ni] = (f32x4){0.f, 0.f, 0.f, 0.f};

#pragma unroll
    for (int ks = 0; ks < 4; ++ks) {
      bf16x8 bf[4];
#pragma unroll
      for (int ni = 0; ni < 4; ++ni) {
        const int nl  = wc * 64 + ni * 16 + l15;   // B row in tile (sim col)
        const int ck  = ks * 4 + q;                // k-chunk 0..15
        const int L   = nl * 16 + (ck ^ (nl & 15));
        bf[ni] = *reinterpret_cast<const bf16x8*>(Bs + L * 8);
      }
#pragma unroll
      for (int mi = 0; mi < 4; ++mi)
#pragma unroll
        for (int ni = 0; ni < 4; ++ni)
          acc[mi][ni] = __builtin_amdgcn_mfma_f32_16x16x32_bf16(
              af[mi][ks], bf[ni], acc[mi][ni], 0, 0, 0);
    }

    // Epilogue: v = exp(sim - 2) = exp2(K1*dot - K1); sum into Srow.
    const bool diag = (ct == rb);          // block-uniform
    const bool part = (ct == (rb ^ 32));   // block-uniform (4096/128 = 32)
#pragma unroll
    for (int mi = 0; mi < 4; ++mi)
#pragma unroll
      for (int ni = 0; ni < 4; ++ni)
#pragma unroll
        for (int r = 0; r < 4; ++r) {
          float d = acc[mi][ni][r];
          float v = __builtin_amdgcn_exp2f(fmaf(d, K1, -K1));
          if (diag) {
            const int rl = wr * 64 + mi * 16 + q * 4 + r;
            const int cl = wc * 64 + ni * 16 + l15;
            if (rl == cl) v = 0.f;
          }
          Srow[mi][r] += v;
        }

    if (part) {
      // partner col local index == row local index (bit-12 toggle)
#pragma unroll
      for (int mi = 0; mi < 4; ++mi) {
        const int rl0 = wr * 64 + mi * 16 + q * 4;
#pragma unroll
        for (int ni = 0; ni < 4; ++ni) {
          const int cl = wc * 64 + ni * 16 + l15;
#pragma unroll
          for (int r = 0; r < 4; ++r) {
            if (cl == rl0 + r)
              P[rb * 128 + rl0 + r] = 2.0f * acc[mi][ni][r];
          }
        }
      }
    }
  }

  // Reduce Srow over the 16 lanes of each quad; one atomicAdd per row.
#pragma unroll
  for (int mi = 0; mi < 4; ++mi)
#pragma unroll
    for (int r = 0; r < 4; ++r) {
      float v = Srow[mi][r];
      v += __shfl_xor(v, 1, 64);
      v += __shfl_xor(v, 2, 64);
      v += __shfl_xor(v, 4, 64);
      v += __shfl_xor(v, 8, 64);
      if (l15 == 0)
        atomicAdd(&S[rb * 128 + wr * 64 + mi * 16 + q * 4 + r], v);
    }
}

// ---------------------------------------------------------------------------
// Kernel 3: loss = mean_i( 2 + log(S_i) - P_i )
// ---------------------------------------------------------------------------
__global__ __launch_bounds__(256) void finalize_kernel(
    const float* __restrict__ S, const float* __restrict__ P,
    float* __restrict__ out)
{
  const int i = blockIdx.x * 256 + threadIdx.x;
  float c = 2.0f + logf(S[i]) - P[i];
#pragma unroll
  for (int off = 1; off < 64; off <<= 1)
    c += __shfl_xor(c, off, 64);
  __shared__ float wsum[4];
  const int lane = threadIdx.x & 63, w = threadIdx.x >> 6;
  if (lane == 0) wsum[w] = c;
  __syncthreads();
  if (threadIdx.x == 0)
    atomicAdd(out, (wsum[0] + wsum[1] + wsum[2] + wsum[3]) * (1.0f / NROWS));
}

// ---------------------------------------------------------------------------
extern "C" void kernel_launch(void* const* d_in, const int* in_sizes, int n_in,
                              void* d_out, int out_size, void* d_ws, size_t ws_size,
                              hipStream_t stream)
{
  const float* zx = (const float*)d_in[0];
  const float* zy = (const float*)d_in[1];
  ushort* zn = (ushort*)d_ws;                                   // 2 MiB bf16
  float*  S  = (float*)((char*)d_ws + (size_t)NROWS * DIM * 2); // 32 KiB
  float*  P  = S + NROWS;                                       // 32 KiB
  float*  out = (float*)d_out;

  hipMemsetAsync(S, 0, NROWS * sizeof(float), stream);
  hipMemsetAsync(out, 0, sizeof(float), stream);
  normalize_kernel<<<NROWS / 4, 256, 0, stream>>>(zx, zy, zn);
  simloss_kernel<<<dim3(64, 8), 256, 0, stream>>>(zn, S, P);
  finalize_kernel<<<NROWS / 256, 256, 0, stream>>>(S, P, out);
}